// Round 11
// baseline (246.601 us; speedup 1.0000x reference)
//
#include <hip/hip_runtime.h>
#include <hip/hip_bf16.h>
#include <math.h>

typedef __bf16 bf16_t;
typedef __bf16 bf16x4_t __attribute__((ext_vector_type(4)));
typedef __bf16 bf16x8 __attribute__((ext_vector_type(8)));
typedef float f32x4 __attribute__((ext_vector_type(4)));
typedef unsigned long long u64;

#define NB 1024
#define NN 75
#define KF 512
#define F1 256
#define HSTR 100   // hT row stride (bf16)
#define ASTR 100   // alp row stride

// ---------------------------------------------------------------------------
// Kernel 0: W [512][256] fp32 -> Wt [256][512] bf16 (transposed, k-contiguous)
// (unchanged, passing)
// ---------------------------------------------------------------------------
__global__ __launch_bounds__(256) void wt_kernel(const float* __restrict__ W,
                                                 bf16_t* __restrict__ Wt) {
    __shared__ float tile[64][65];
    const int kb = blockIdx.x * 64;
    const int nb = blockIdx.y * 64;
    const int tc = threadIdx.x & 63;
    const int tr = threadIdx.x >> 6;
#pragma unroll
    for (int r = tr; r < 64; r += 4)
        tile[r][tc] = W[(size_t)(kb + r) * F1 + nb + tc];
    __syncthreads();
#pragma unroll
    for (int r = tr; r < 64; r += 4)
        Wt[(size_t)(nb + r) * KF + kb + tc] = (bf16_t)tile[tc][r];
}

// ---------------------------------------------------------------------------
// Kernel 1 (barrier-free): h = X @ W -> out[...,256:512].
// Wave w owns rows [m0+w*16, m0+w*16+16), ALL 256 cols. A-fragments direct
// from global (disjoint rows -> no duplication), W-fragments direct from
// L2/L1-hot Wt (4 waves share the same 16KB/step slice via L1). No LDS, no
// __syncthreads. X depth-1 register prefetch; W in 2 batches of 8 frags.
// ---------------------------------------------------------------------------
__global__ __launch_bounds__(256) void gemm_kernel(const float* __restrict__ X,
                                                   const bf16_t* __restrict__ Wt,
                                                   float* __restrict__ out) {
    const int t = threadIdx.x;
    const int w = t >> 6;
    const int l = t & 63;
    const int lc = l & 15;
    const int lr = l >> 4;
    const int m0 = blockIdx.x * 64;

    // A: lane l covers row (m0 + w*16 + lc), k-chunk lr*8 (+ks*32)
    const float* xsrc = X + (size_t)(m0 + w * 16 + lc) * KF + lr * 8;
    // B: lane l covers Wt row (nt*16 + lc), k-chunk lr*8 (+ks*32)
    const bf16_t* wbase = Wt + (size_t)lc * KF + lr * 8;

    f32x4 acc[16];
#pragma unroll
    for (int i = 0; i < 16; ++i) acc[i] = (f32x4){0.f, 0.f, 0.f, 0.f};

    float4 xa = *(const float4*)xsrc;
    float4 xb = *(const float4*)(xsrc + 4);

#pragma unroll
    for (int ks = 0; ks < 16; ++ks) {
        // pack current A fragment
        bf16x8 af;
        af[0] = (bf16_t)xa.x; af[1] = (bf16_t)xa.y;
        af[2] = (bf16_t)xa.z; af[3] = (bf16_t)xa.w;
        af[4] = (bf16_t)xb.x; af[5] = (bf16_t)xb.y;
        af[6] = (bf16_t)xb.z; af[7] = (bf16_t)xb.w;
        // prefetch next step's A (HBM) immediately
        if (ks < 15) {
            xa = *(const float4*)(xsrc + (ks + 1) * 32);
            xb = *(const float4*)(xsrc + (ks + 1) * 32 + 4);
        }
        // W frags + MFMA in two batches of 8 (caps VGPR, overlaps ld/mfma)
#pragma unroll
        for (int h = 0; h < 2; ++h) {
            bf16x8 wf[8];
#pragma unroll
            for (int nt = 0; nt < 8; ++nt)
                wf[nt] = *(const bf16x8*)(wbase + (size_t)(h * 8 + nt) * 16 * KF + ks * 32);
#pragma unroll
            for (int nt = 0; nt < 8; ++nt)
                acc[h * 8 + nt] = __builtin_amdgcn_mfma_f32_16x16x32_bf16(
                    af, wf[nt], acc[h * 8 + nt], 0, 0, 0);
        }
    }

    // epilogue: D row = lr*4 + j (within wave's 16 rows), col = nt*16 + lc
#pragma unroll
    for (int nt = 0; nt < 16; ++nt) {
#pragma unroll
        for (int j = 0; j < 4; ++j) {
            const int row = m0 + w * 16 + lr * 4 + j;
            out[(size_t)row * 512 + 256 + nt * 16 + lc] = acc[nt][j];
        }
    }
}

// ---------------------------------------------------------------------------
// Kernel 2: per-batch attention (EXACT round-8 body, passing).
// ---------------------------------------------------------------------------
__global__ __launch_bounds__(256) void pv_kernel(const int* __restrict__ Adj,
                                                 const float* __restrict__ avec,
                                                 float* __restrict__ out) {
    __shared__ __align__(16) bf16_t hT[256 * HSTR];   // 51200 B
    __shared__ __align__(16) bf16_t alp[80 * ASTR];   // 16000 B
    __shared__ float a0s[F1], a1s[F1];
    __shared__ float attp0[4][80], attp1[4][80];
    __shared__ float att0s[80], att1s[80], rsums[80];
    __shared__ u64 adjb[160];

    const int b = blockIdx.x;
    const int t = threadIdx.x;
    const int w = t >> 6;
    const int l = t & 63;
    const int lc = l & 15;
    const int lr = l >> 4;
    float* outb = out + (size_t)b * NN * 512;

    // ---- phase 0: a-vectors, adjacency bitmask, hT k-pad zero ----
    a0s[t] = avec[t];
    a1s[t] = avec[F1 + t];
    for (int i = w; i < NN; i += 4) {
        const int v0 = Adj[i * NN + l];
        const int v1 = (l < NN - 64) ? Adj[i * NN + 64 + l] : 0;
        const u64 b0 = __ballot(v0 != 0);
        const u64 b1 = __ballot(v1 != 0);
        if (l == 0) { adjb[i * 2] = b0; adjb[i * 2 + 1] = b1; }
    }
    {
        int* z = (int*)&hT[t * HSTR + 80];
#pragma unroll
        for (int k = 0; k < 8; ++k) z[k] = 0;
    }
    __syncthreads();

    // ---- phase T: load h + att partials + transpose ----
    const int c0 = w * 64 + lc * 4;
    const float4 a04 = *(const float4*)&a0s[c0];
    const float4 a14 = *(const float4*)&a1s[c0];
#pragma unroll
    for (int jp = 0; jp < 5; ++jp) {
        const int j0 = jp * 16 + lr * 4;
        float hr[4][4];
#pragma unroll
        for (int r = 0; r < 4; ++r) {
            if (j0 + r < NN) {
                const float4 v = *(const float4*)(outb + (size_t)(j0 + r) * 512 + 256 + c0);
                hr[r][0] = v.x; hr[r][1] = v.y; hr[r][2] = v.z; hr[r][3] = v.w;
            } else {
                hr[r][0] = hr[r][1] = hr[r][2] = hr[r][3] = 0.f;
            }
        }
        float p0[4], p1[4];
#pragma unroll
        for (int r = 0; r < 4; ++r) {
            p0[r] = hr[r][0] * a04.x + hr[r][1] * a04.y + hr[r][2] * a04.z + hr[r][3] * a04.w;
            p1[r] = hr[r][0] * a14.x + hr[r][1] * a14.y + hr[r][2] * a14.z + hr[r][3] * a14.w;
        }
#pragma unroll
        for (int off = 1; off < 16; off <<= 1) {
#pragma unroll
            for (int r = 0; r < 4; ++r) {
                p0[r] += __shfl_xor(p0[r], off);
                p1[r] += __shfl_xor(p1[r], off);
            }
        }
        if (lc == 0) {
#pragma unroll
            for (int r = 0; r < 4; ++r) {
                attp0[w][j0 + r] = p0[r];
                attp1[w][j0 + r] = p1[r];
            }
        }
#pragma unroll
        for (int cc = 0; cc < 4; ++cc) {
            bf16x4_t v;
            v[0] = (bf16_t)hr[0][cc]; v[1] = (bf16_t)hr[1][cc];
            v[2] = (bf16_t)hr[2][cc]; v[3] = (bf16_t)hr[3][cc];
            *(bf16x4_t*)&hT[(c0 + cc) * HSTR + j0] = v;
        }
    }
    __syncthreads();

    // ---- phase 1b ----
    if (t < 80)
        att0s[t] = attp0[0][t] + attp0[1][t] + attp0[2][t] + attp0[3][t];
    else if (t < 160)
        att1s[t - 80] = attp1[0][t - 80] + attp1[1][t - 80] + attp1[2][t - 80] + attp1[3][t - 80];
    else if (t < 240) {
        const int r = t - 160;
        if (r < NN) {
            for (int c = NN; c < 96; ++c) alp[r * ASTR + c] = (bf16_t)0.f;
        } else {
            for (int c = 0; c < 96; ++c) alp[r * ASTR + c] = (bf16_t)0.f;
        }
    }
    __syncthreads();

    // ---- phase S ----
    {
        const int gid = t >> 2;
        const int k4 = t & 3;
#pragma unroll
        for (int r = 0; r < 2; ++r) {
            const int i = r * 64 + gid;
            if (i < NN) {
                const float a0i = att0s[i];
                const u64 w0 = adjb[i * 2];
                const u64 w1 = adjb[i * 2 + 1];
                float e[19];
                float m = -3.0e38f;
#pragma unroll
                for (int jj = 0; jj < 19; ++jj) {
                    const int j = jj * 4 + k4;
                    float ev = -3.0e38f;
                    if (j < NN) {
                        float x = a0i + att1s[j];
                        x = x > 0.f ? x : 0.2f * x;
                        const u64 wj = (j < 64) ? w0 : w1;
                        const int bit = (int)((wj >> (j & 63)) & 1);
                        ev = bit ? x : x - 1.0e9f;
                    }
                    e[jj] = ev;
                    m = fmaxf(m, ev);
                }
                m = fmaxf(m, __shfl_xor(m, 1));
                m = fmaxf(m, __shfl_xor(m, 2));
                float s = 0.f;
#pragma unroll
                for (int jj = 0; jj < 19; ++jj) {
                    const int j = jj * 4 + k4;
                    if (j < NN) {
                        const float ex = __expf(e[jj] - m);
                        s += ex;
                        alp[i * ASTR + j] = (bf16_t)ex;
                    }
                }
                s += __shfl_xor(s, 1);
                s += __shfl_xor(s, 2);
                if (k4 == 0) rsums[i] = 1.f / s;
            }
        }
    }
    __syncthreads();

    // ---- phase P ----
    f32x4 acc2[5][4];
#pragma unroll
    for (int i = 0; i < 5; ++i)
#pragma unroll
        for (int j = 0; j < 4; ++j) acc2[i][j] = (f32x4){0.f, 0.f, 0.f, 0.f};

#pragma unroll
    for (int ks = 0; ks < 3; ++ks) {
        bf16x8 bv[4];
#pragma unroll
        for (int ntl = 0; ntl < 4; ++ntl) {
            const bf16_t* q = &hT[(w * 64 + ntl * 16 + lc) * HSTR + ks * 32 + lr * 8];
            ((uint2*)&bv[ntl])[0] = *(const uint2*)q;
            ((uint2*)&bv[ntl])[1] = *(const uint2*)(q + 4);
        }
#pragma unroll
        for (int mt = 0; mt < 5; ++mt) {
            const bf16_t* ap = &alp[(mt * 16 + lc) * ASTR + ks * 32 + lr * 8];
            bf16x8 av;
            ((uint2*)&av)[0] = *(const uint2*)ap;
            ((uint2*)&av)[1] = *(const uint2*)(ap + 4);
#pragma unroll
            for (int ntl = 0; ntl < 4; ++ntl)
                acc2[mt][ntl] = __builtin_amdgcn_mfma_f32_16x16x32_bf16(av, bv[ntl], acc2[mt][ntl], 0, 0, 0);
        }
    }

    // ---- epilogue ----
#pragma unroll
    for (int mt = 0; mt < 5; ++mt) {
#pragma unroll
        for (int j = 0; j < 4; ++j) {
            const int row = mt * 16 + lr * 4 + j;
            if (row < NN) {
                const float rsv = rsums[row];
#pragma unroll
                for (int ntl = 0; ntl < 4; ++ntl) {
                    const int ch = w * 64 + ntl * 16 + lc;
                    outb[(size_t)row * 512 + ch] = acc2[mt][ntl][j] * rsv;
                }
            }
        }
    }
}

// ---------------------------------------------------------------------------
extern "C" void kernel_launch(void* const* d_in, const int* in_sizes, int n_in,
                              void* d_out, int out_size, void* d_ws, size_t ws_size,
                              hipStream_t stream) {
    const float* X = (const float*)d_in[0];   // [1024,75,512] f32
    const int*   A = (const int*)d_in[1];     // [75,75] i32
    const float* W = (const float*)d_in[2];   // [512,256] f32
    const float* a = (const float*)d_in[3];   // [2,256,1] f32
    float* out = (float*)d_out;               // [1024,75,512] f32
    bf16_t* Wt = (bf16_t*)d_ws;               // 256 KB scratch

    wt_kernel<<<dim3(KF / 64, F1 / 64), 256, 0, stream>>>(W, Wt);
    gemm_kernel<<<(NB * NN) / 64, 256, 0, stream>>>(X, Wt, out);
    pv_kernel<<<NB, 256, 0, stream>>>(A, a, out);
}

// Round 12
// 131.827 us; speedup vs baseline: 1.8706x; 1.8706x over previous
//
#include <hip/hip_runtime.h>
#include <hip/hip_bf16.h>
#include <math.h>

typedef __bf16 bf16_t;
typedef __bf16 bf16x4_t __attribute__((ext_vector_type(4)));
typedef __bf16 bf16x8 __attribute__((ext_vector_type(8)));
typedef float f32x4 __attribute__((ext_vector_type(4)));
typedef unsigned long long u64;

#define NB 1024
#define NN 75
#define KF 512
#define F1 256
#define HSTR 100   // hT row stride (bf16)
#define ASTR 100   // alp row stride

// ---------------------------------------------------------------------------
// Kernel 0: W [512][256] fp32 -> Wt [256][512] bf16 (unchanged, passing)
// ---------------------------------------------------------------------------
__global__ __launch_bounds__(256) void wt_kernel(const float* __restrict__ W,
                                                 bf16_t* __restrict__ Wt) {
    __shared__ float tile[64][65];
    const int kb = blockIdx.x * 64;
    const int nb = blockIdx.y * 64;
    const int tc = threadIdx.x & 63;
    const int tr = threadIdx.x >> 6;
#pragma unroll
    for (int r = tr; r < 64; r += 4)
        tile[r][tc] = W[(size_t)(kb + r) * F1 + nb + tc];
    __syncthreads();
#pragma unroll
    for (int r = tr; r < 64; r += 4)
        Wt[(size_t)(nb + r) * KF + kb + tc] = (bf16_t)tile[tc][r];
}

// ---------------------------------------------------------------------------
// Kernel 1: h = X @ W -> out[...,256:512].
// Full-K X tile burst-staged into 64KB LDS (fragment-order, 32 independent
// float4 loads/thread), ONE barrier, then 16 MFMA steps with zero barriers.
// W fragments via r10's register double-buffer from L2-hot Wt.
// ---------------------------------------------------------------------------
__global__ __launch_bounds__(256) void gemm_kernel(const float* __restrict__ X,
                                                   const bf16_t* __restrict__ Wt,
                                                   float* __restrict__ out) {
    __shared__ __align__(16) bf16_t Xs[64 * 512];   // 65536 B

    const int t = threadIdx.x;
    const int w = t >> 6;
    const int l = t & 63;
    const int lc = l & 15;
    const int lr = l >> 4;
    const int m0 = blockIdx.x * 64;

    // W direct fragment pointers (per-wave disjoint cols)
    const bf16_t* wp0 = Wt + (size_t)(w * 64 + 0 * 16 + lc) * KF + lr * 8;
    const bf16_t* wp1 = Wt + (size_t)(w * 64 + 1 * 16 + lc) * KF + lr * 8;
    const bf16_t* wp2 = Wt + (size_t)(w * 64 + 2 * 16 + lc) * KF + lr * 8;
    const bf16_t* wp3 = Wt + (size_t)(w * 64 + 3 * 16 + lc) * KF + lr * 8;

    bf16x8 wA[4], wB[4];
#define WLOAD(WREG, KS)                                        \
    WREG[0] = *(const bf16x8*)(wp0 + (KS) * 32);               \
    WREG[1] = *(const bf16x8*)(wp1 + (KS) * 32);               \
    WREG[2] = *(const bf16x8*)(wp2 + (KS) * 32);               \
    WREG[3] = *(const bf16x8*)(wp3 + (KS) * 32);

    WLOAD(wA, 0);   // W step-0 prefetch overlaps X staging

    // X staging: thread t owns row (t>>6)*16+(t&15), k-subchunk ((t>>4)&3)*8;
    // for each step q it fills chunk (q*256 + t) -> LDS byte (q*256+t)*16.
    const int xrow  = ((t >> 6) << 4) + (t & 15);
    const int kpart = ((t >> 4) & 3) * 8;
    const float* xsrc = X + (size_t)(m0 + xrow) * KF + kpart;
#pragma unroll
    for (int q = 0; q < 16; ++q) {
        const float4 xa = *(const float4*)(xsrc + q * 32);
        const float4 xb = *(const float4*)(xsrc + q * 32 + 4);
        bf16x8 v;
        v[0]=(bf16_t)xa.x; v[1]=(bf16_t)xa.y; v[2]=(bf16_t)xa.z; v[3]=(bf16_t)xa.w;
        v[4]=(bf16_t)xb.x; v[5]=(bf16_t)xb.y; v[6]=(bf16_t)xb.z; v[7]=(bf16_t)xb.w;
        *(bf16x8*)&Xs[(q * 256 + t) * 8] = v;
    }
    __syncthreads();   // the ONLY barrier

    f32x4 acc[4][4];
#pragma unroll
    for (int i = 0; i < 4; ++i)
#pragma unroll
        for (int j = 0; j < 4; ++j) acc[i][j] = (f32x4){0.f, 0.f, 0.f, 0.f};

#define GSTEP(KS, WREG)                                                        \
    {                                                                          \
        bf16x8 af[4];                                                          \
        _Pragma("unroll")                                                      \
        for (int mt = 0; mt < 4; ++mt)                                         \
            af[mt] = *(const bf16x8*)&Xs[((KS) * 256 + mt * 64 + l) * 8];      \
        _Pragma("unroll")                                                      \
        for (int mt = 0; mt < 4; ++mt)                                         \
            _Pragma("unroll")                                                  \
            for (int ntl = 0; ntl < 4; ++ntl)                                  \
                acc[mt][ntl] = __builtin_amdgcn_mfma_f32_16x16x32_bf16(        \
                    af[mt], WREG[ntl], acc[mt][ntl], 0, 0, 0);                 \
    }

#pragma unroll
    for (int kp = 0; kp < 8; ++kp) {
        const int ks0 = kp * 2;
        const int ks1 = kp * 2 + 1;
        WLOAD(wB, ks1);
        GSTEP(ks0, wA);
        if (ks1 < 15) { WLOAD(wA, ks1 + 1); }
        GSTEP(ks1, wB);
    }
#undef GSTEP
#undef WLOAD

    // epilogue: D row = mt*16 + lr*4 + j, col = w*64 + ntl*16 + lc
#pragma unroll
    for (int mt = 0; mt < 4; ++mt) {
#pragma unroll
        for (int ntl = 0; ntl < 4; ++ntl) {
            const int col = w * 64 + ntl * 16 + lc;
#pragma unroll
            for (int j = 0; j < 4; ++j) {
                const int row = m0 + mt * 16 + lr * 4 + j;
                out[(size_t)row * 512 + 256 + col] = acc[mt][ntl][j];
            }
        }
    }
}

// ---------------------------------------------------------------------------
// Kernel 2: per-batch attention (EXACT round-8 body, passing).
// ---------------------------------------------------------------------------
__global__ __launch_bounds__(256) void pv_kernel(const int* __restrict__ Adj,
                                                 const float* __restrict__ avec,
                                                 float* __restrict__ out) {
    __shared__ __align__(16) bf16_t hT[256 * HSTR];   // 51200 B
    __shared__ __align__(16) bf16_t alp[80 * ASTR];   // 16000 B
    __shared__ float a0s[F1], a1s[F1];
    __shared__ float attp0[4][80], attp1[4][80];
    __shared__ float att0s[80], att1s[80], rsums[80];
    __shared__ u64 adjb[160];

    const int b = blockIdx.x;
    const int t = threadIdx.x;
    const int w = t >> 6;
    const int l = t & 63;
    const int lc = l & 15;
    const int lr = l >> 4;
    float* outb = out + (size_t)b * NN * 512;

    // ---- phase 0 ----
    a0s[t] = avec[t];
    a1s[t] = avec[F1 + t];
    for (int i = w; i < NN; i += 4) {
        const int v0 = Adj[i * NN + l];
        const int v1 = (l < NN - 64) ? Adj[i * NN + 64 + l] : 0;
        const u64 b0 = __ballot(v0 != 0);
        const u64 b1 = __ballot(v1 != 0);
        if (l == 0) { adjb[i * 2] = b0; adjb[i * 2 + 1] = b1; }
    }
    {
        int* z = (int*)&hT[t * HSTR + 80];
#pragma unroll
        for (int k = 0; k < 8; ++k) z[k] = 0;
    }
    __syncthreads();

    // ---- phase T ----
    const int c0 = w * 64 + lc * 4;
    const float4 a04 = *(const float4*)&a0s[c0];
    const float4 a14 = *(const float4*)&a1s[c0];
#pragma unroll
    for (int jp = 0; jp < 5; ++jp) {
        const int j0 = jp * 16 + lr * 4;
        float hr[4][4];
#pragma unroll
        for (int r = 0; r < 4; ++r) {
            if (j0 + r < NN) {
                const float4 v = *(const float4*)(outb + (size_t)(j0 + r) * 512 + 256 + c0);
                hr[r][0] = v.x; hr[r][1] = v.y; hr[r][2] = v.z; hr[r][3] = v.w;
            } else {
                hr[r][0] = hr[r][1] = hr[r][2] = hr[r][3] = 0.f;
            }
        }
        float p0[4], p1[4];
#pragma unroll
        for (int r = 0; r < 4; ++r) {
            p0[r] = hr[r][0] * a04.x + hr[r][1] * a04.y + hr[r][2] * a04.z + hr[r][3] * a04.w;
            p1[r] = hr[r][0] * a14.x + hr[r][1] * a14.y + hr[r][2] * a14.z + hr[r][3] * a14.w;
        }
#pragma unroll
        for (int off = 1; off < 16; off <<= 1) {
#pragma unroll
            for (int r = 0; r < 4; ++r) {
                p0[r] += __shfl_xor(p0[r], off);
                p1[r] += __shfl_xor(p1[r], off);
            }
        }
        if (lc == 0) {
#pragma unroll
            for (int r = 0; r < 4; ++r) {
                attp0[w][j0 + r] = p0[r];
                attp1[w][j0 + r] = p1[r];
            }
        }
#pragma unroll
        for (int cc = 0; cc < 4; ++cc) {
            bf16x4_t v;
            v[0] = (bf16_t)hr[0][cc]; v[1] = (bf16_t)hr[1][cc];
            v[2] = (bf16_t)hr[2][cc]; v[3] = (bf16_t)hr[3][cc];
            *(bf16x4_t*)&hT[(c0 + cc) * HSTR + j0] = v;
        }
    }
    __syncthreads();

    // ---- phase 1b ----
    if (t < 80)
        att0s[t] = attp0[0][t] + attp0[1][t] + attp0[2][t] + attp0[3][t];
    else if (t < 160)
        att1s[t - 80] = attp1[0][t - 80] + attp1[1][t - 80] + attp1[2][t - 80] + attp1[3][t - 80];
    else if (t < 240) {
        const int r = t - 160;
        if (r < NN) {
            for (int c = NN; c < 96; ++c) alp[r * ASTR + c] = (bf16_t)0.f;
        } else {
            for (int c = 0; c < 96; ++c) alp[r * ASTR + c] = (bf16_t)0.f;
        }
    }
    __syncthreads();

    // ---- phase S ----
    {
        const int gid = t >> 2;
        const int k4 = t & 3;
#pragma unroll
        for (int r = 0; r < 2; ++r) {
            const int i = r * 64 + gid;
            if (i < NN) {
                const float a0i = att0s[i];
                const u64 w0 = adjb[i * 2];
                const u64 w1 = adjb[i * 2 + 1];
                float e[19];
                float m = -3.0e38f;
#pragma unroll
                for (int jj = 0; jj < 19; ++jj) {
                    const int j = jj * 4 + k4;
                    float ev = -3.0e38f;
                    if (j < NN) {
                        float x = a0i + att1s[j];
                        x = x > 0.f ? x : 0.2f * x;
                        const u64 wj = (j < 64) ? w0 : w1;
                        const int bit = (int)((wj >> (j & 63)) & 1);
                        ev = bit ? x : x - 1.0e9f;
                    }
                    e[jj] = ev;
                    m = fmaxf(m, ev);
                }
                m = fmaxf(m, __shfl_xor(m, 1));
                m = fmaxf(m, __shfl_xor(m, 2));
                float s = 0.f;
#pragma unroll
                for (int jj = 0; jj < 19; ++jj) {
                    const int j = jj * 4 + k4;
                    if (j < NN) {
                        const float ex = __expf(e[jj] - m);
                        s += ex;
                        alp[i * ASTR + j] = (bf16_t)ex;
                    }
                }
                s += __shfl_xor(s, 1);
                s += __shfl_xor(s, 2);
                if (k4 == 0) rsums[i] = 1.f / s;
            }
        }
    }
    __syncthreads();

    // ---- phase P ----
    f32x4 acc2[5][4];
#pragma unroll
    for (int i = 0; i < 5; ++i)
#pragma unroll
        for (int j = 0; j < 4; ++j) acc2[i][j] = (f32x4){0.f, 0.f, 0.f, 0.f};

#pragma unroll
    for (int ks = 0; ks < 3; ++ks) {
        bf16x8 bv[4];
#pragma unroll
        for (int ntl = 0; ntl < 4; ++ntl) {
            const bf16_t* q = &hT[(w * 64 + ntl * 16 + lc) * HSTR + ks * 32 + lr * 8];
            ((uint2*)&bv[ntl])[0] = *(const uint2*)q;
            ((uint2*)&bv[ntl])[1] = *(const uint2*)(q + 4);
        }
#pragma unroll
        for (int mt = 0; mt < 5; ++mt) {
            const bf16_t* ap = &alp[(mt * 16 + lc) * ASTR + ks * 32 + lr * 8];
            bf16x8 av;
            ((uint2*)&av)[0] = *(const uint2*)ap;
            ((uint2*)&av)[1] = *(const uint2*)(ap + 4);
#pragma unroll
            for (int ntl = 0; ntl < 4; ++ntl)
                acc2[mt][ntl] = __builtin_amdgcn_mfma_f32_16x16x32_bf16(av, bv[ntl], acc2[mt][ntl], 0, 0, 0);
        }
    }

    // ---- epilogue ----
#pragma unroll
    for (int mt = 0; mt < 5; ++mt) {
#pragma unroll
        for (int j = 0; j < 4; ++j) {
            const int row = mt * 16 + lr * 4 + j;
            if (row < NN) {
                const float rsv = rsums[row];
#pragma unroll
                for (int ntl = 0; ntl < 4; ++ntl) {
                    const int ch = w * 64 + ntl * 16 + lc;
                    outb[(size_t)row * 512 + ch] = acc2[mt][ntl][j] * rsv;
                }
            }
        }
    }
}

// ---------------------------------------------------------------------------
extern "C" void kernel_launch(void* const* d_in, const int* in_sizes, int n_in,
                              void* d_out, int out_size, void* d_ws, size_t ws_size,
                              hipStream_t stream) {
    const float* X = (const float*)d_in[0];   // [1024,75,512] f32
    const int*   A = (const int*)d_in[1];     // [75,75] i32
    const float* W = (const float*)d_in[2];   // [512,256] f32
    const float* a = (const float*)d_in[3];   // [2,256,1] f32
    float* out = (float*)d_out;               // [1024,75,512] f32
    bf16_t* Wt = (bf16_t*)d_ws;               // 256 KB scratch

    wt_kernel<<<dim3(KF / 64, F1 / 64), 256, 0, stream>>>(W, Wt);
    gemm_kernel<<<(NB * NN) / 64, 256, 0, stream>>>(X, Wt, out);
    pv_kernel<<<NB, 256, 0, stream>>>(A, a, out);
}

// Round 13
// 131.681 us; speedup vs baseline: 1.8727x; 1.0011x over previous
//
#include <hip/hip_runtime.h>
#include <hip/hip_bf16.h>
#include <math.h>

typedef __bf16 bf16_t;
typedef __bf16 bf16x4_t __attribute__((ext_vector_type(4)));
typedef __bf16 bf16x8 __attribute__((ext_vector_type(8)));
typedef float f32x4 __attribute__((ext_vector_type(4)));
typedef unsigned long long u64;

typedef __attribute__((address_space(1))) const unsigned int cu32_g;
typedef __attribute__((address_space(3))) unsigned int u32_s;

#define NB 1024
#define NN 75
#define KF 512
#define F1 256
#define HSTR 100   // hT row stride (bf16)
#define ASTR 100   // alp row stride

// ---------------------------------------------------------------------------
// Kernel 0: W [512][256] fp32 -> Wt [256][512] bf16 (unchanged, passing)
// ---------------------------------------------------------------------------
__global__ __launch_bounds__(256) void wt_kernel(const float* __restrict__ W,
                                                 bf16_t* __restrict__ Wt) {
    __shared__ float tile[64][65];
    const int kb = blockIdx.x * 64;
    const int nb = blockIdx.y * 64;
    const int tc = threadIdx.x & 63;
    const int tr = threadIdx.x >> 6;
#pragma unroll
    for (int r = tr; r < 64; r += 4)
        tile[r][tc] = W[(size_t)(kb + r) * F1 + nb + tc];
    __syncthreads();
#pragma unroll
    for (int r = tr; r < 64; r += 4)
        Wt[(size_t)(nb + r) * KF + kb + tc] = (bf16_t)tile[tc][r];
}

// ---------------------------------------------------------------------------
// Kernel 1: h = X @ W -> out[...,256:512].
// X staged fp32 via global_load_lds(16B) into BK=64 double buffer (2x16KB),
// XOR-swizzled (linear LDS dest + inverse-swizzled global source + swizzled
// read). fp32->bf16 cvt at fragment read (VALU idle). W via r10 register
// double-buffer from L2-hot Wt. One barrier per BK step.
// ---------------------------------------------------------------------------
__global__ __launch_bounds__(256, 3) void gemm_kernel(const float* __restrict__ X,
                                                      const bf16_t* __restrict__ Wt,
                                                      float* __restrict__ out) {
    __shared__ __align__(16) float XsF[2 * 4096];   // 2 x 64 rows x 64 floats

    const int t = threadIdx.x;
    const int w = t >> 6;
    const int l = t & 63;
    const int lc = l & 15;
    const int lr = l >> 4;
    const int m0 = blockIdx.x * 64;

    // ---- staging geometry ----
    // issue u (0..3): wave covers LDS slots p = (u*4+w)*64 + l (16B each),
    // i.e. row = u*16 + c (c = w*4 + (l>>4)), physical slot s = l&15.
    // physical slot s of row r holds logical slot sd = s ^ (r&7).
    const int c_row = w * 4 + lr;
    const int sd    = (l & 15) ^ (c_row & 7);       // (u*16) & 7 == 0
    const float* gsrc = X + (size_t)(m0 + c_row) * KF + sd * 4;

#define STAGE(BUF, KS64)                                                       \
    {                                                                          \
        _Pragma("unroll")                                                      \
        for (int u = 0; u < 4; ++u) {                                          \
            const float* g = gsrc + (size_t)u * 16 * KF + (KS64) * 64;         \
            float* lp = XsF + (BUF) * 4096 + (u * 4 + w) * 256;                \
            __builtin_amdgcn_global_load_lds((cu32_g*)g, (u32_s*)lp, 16, 0, 0);\
        }                                                                      \
    }

    // ---- W register double-buffer (r10 proven) ----
    const bf16_t* wp0 = Wt + (size_t)(w * 64 + 0 * 16 + lc) * KF + lr * 8;
    const bf16_t* wp1 = Wt + (size_t)(w * 64 + 1 * 16 + lc) * KF + lr * 8;
    const bf16_t* wp2 = Wt + (size_t)(w * 64 + 2 * 16 + lc) * KF + lr * 8;
    const bf16_t* wp3 = Wt + (size_t)(w * 64 + 3 * 16 + lc) * KF + lr * 8;
    bf16x8 wA[4], wB[4];
#define WLOAD(WREG, KS32)                                      \
    WREG[0] = *(const bf16x8*)(wp0 + (KS32) * 32);             \
    WREG[1] = *(const bf16x8*)(wp1 + (KS32) * 32);             \
    WREG[2] = *(const bf16x8*)(wp2 + (KS32) * 32);             \
    WREG[3] = *(const bf16x8*)(wp3 + (KS32) * 32);

    f32x4 acc[4][4];
#pragma unroll
    for (int i = 0; i < 4; ++i)
#pragma unroll
        for (int j = 0; j < 4; ++j) acc[i][j] = (f32x4){0.f, 0.f, 0.f, 0.f};

    // fragment read: row_local = mt*16+lc, logical slots s0,s0+1 where
    // s0 = (KO>>2) + lr*2; physical = logical ^ (row&7).
#define GSTEP32(BUF, KO, WREG)                                                 \
    {                                                                          \
        bf16x8 af[4];                                                          \
        _Pragma("unroll")                                                      \
        for (int mt = 0; mt < 4; ++mt) {                                       \
            const int rowl = mt * 16 + lc;                                     \
            const int xr = rowl & 7;                                           \
            const int s0 = ((KO) >> 2) + lr * 2;                               \
            const float4 fa = *(const float4*)&XsF[(BUF) * 4096 + rowl * 64 +  \
                                                   ((s0 ^ xr) << 2)];          \
            const float4 fb = *(const float4*)&XsF[(BUF) * 4096 + rowl * 64 +  \
                                                   (((s0 + 1) ^ xr) << 2)];    \
            af[mt][0] = (bf16_t)fa.x; af[mt][1] = (bf16_t)fa.y;                \
            af[mt][2] = (bf16_t)fa.z; af[mt][3] = (bf16_t)fa.w;                \
            af[mt][4] = (bf16_t)fb.x; af[mt][5] = (bf16_t)fb.y;                \
            af[mt][6] = (bf16_t)fb.z; af[mt][7] = (bf16_t)fb.w;                \
        }                                                                      \
        _Pragma("unroll")                                                      \
        for (int mt = 0; mt < 4; ++mt)                                         \
            _Pragma("unroll")                                                  \
            for (int ntl = 0; ntl < 4; ++ntl)                                  \
                acc[mt][ntl] = __builtin_amdgcn_mfma_f32_16x16x32_bf16(        \
                    af[mt], WREG[ntl], acc[mt][ntl], 0, 0, 0);                 \
    }

    // ---- prologue ----
    WLOAD(wA, 0);
    STAGE(0, 0);
    __syncthreads();   // drains vmcnt -> buf0 ready

    int buf = 0;
#pragma unroll
    for (int ks64 = 0; ks64 < 8; ++ks64) {
        if (ks64 < 7) STAGE(buf ^ 1, ks64 + 1);   // async into other buffer
        WLOAD(wB, 2 * ks64 + 1);
        GSTEP32(buf, 0, wA);
        if (2 * ks64 + 2 < 16) { WLOAD(wA, 2 * ks64 + 2); }
        GSTEP32(buf, 32, wB);
        __syncthreads();   // waits vmcnt(0): next buffer staged; reads done
        buf ^= 1;
    }
#undef GSTEP32
#undef WLOAD
#undef STAGE

    // ---- epilogue: D row = mt*16 + lr*4 + j, col = w*64 + ntl*16 + lc ----
#pragma unroll
    for (int mt = 0; mt < 4; ++mt) {
#pragma unroll
        for (int ntl = 0; ntl < 4; ++ntl) {
            const int col = w * 64 + ntl * 16 + lc;
#pragma unroll
            for (int j = 0; j < 4; ++j) {
                const int row = m0 + mt * 16 + lr * 4 + j;
                out[(size_t)row * 512 + 256 + col] = acc[mt][ntl][j];
            }
        }
    }
}

// ---------------------------------------------------------------------------
// Kernel 2: per-batch attention (EXACT round-8 body, passing).
// ---------------------------------------------------------------------------
__global__ __launch_bounds__(256) void pv_kernel(const int* __restrict__ Adj,
                                                 const float* __restrict__ avec,
                                                 float* __restrict__ out) {
    __shared__ __align__(16) bf16_t hT[256 * HSTR];   // 51200 B
    __shared__ __align__(16) bf16_t alp[80 * ASTR];   // 16000 B
    __shared__ float a0s[F1], a1s[F1];
    __shared__ float attp0[4][80], attp1[4][80];
    __shared__ float att0s[80], att1s[80], rsums[80];
    __shared__ u64 adjb[160];

    const int b = blockIdx.x;
    const int t = threadIdx.x;
    const int w = t >> 6;
    const int l = t & 63;
    const int lc = l & 15;
    const int lr = l >> 4;
    float* outb = out + (size_t)b * NN * 512;

    // ---- phase 0 ----
    a0s[t] = avec[t];
    a1s[t] = avec[F1 + t];
    for (int i = w; i < NN; i += 4) {
        const int v0 = Adj[i * NN + l];
        const int v1 = (l < NN - 64) ? Adj[i * NN + 64 + l] : 0;
        const u64 b0 = __ballot(v0 != 0);
        const u64 b1 = __ballot(v1 != 0);
        if (l == 0) { adjb[i * 2] = b0; adjb[i * 2 + 1] = b1; }
    }
    {
        int* z = (int*)&hT[t * HSTR + 80];
#pragma unroll
        for (int k = 0; k < 8; ++k) z[k] = 0;
    }
    __syncthreads();

    // ---- phase T ----
    const int c0 = w * 64 + lc * 4;
    const float4 a04 = *(const float4*)&a0s[c0];
    const float4 a14 = *(const float4*)&a1s[c0];
#pragma unroll
    for (int jp = 0; jp < 5; ++jp) {
        const int j0 = jp * 16 + lr * 4;
        float hr[4][4];
#pragma unroll
        for (int r = 0; r < 4; ++r) {
            if (j0 + r < NN) {
                const float4 v = *(const float4*)(outb + (size_t)(j0 + r) * 512 + 256 + c0);
                hr[r][0] = v.x; hr[r][1] = v.y; hr[r][2] = v.z; hr[r][3] = v.w;
            } else {
                hr[r][0] = hr[r][1] = hr[r][2] = hr[r][3] = 0.f;
            }
        }
        float p0[4], p1[4];
#pragma unroll
        for (int r = 0; r < 4; ++r) {
            p0[r] = hr[r][0] * a04.x + hr[r][1] * a04.y + hr[r][2] * a04.z + hr[r][3] * a04.w;
            p1[r] = hr[r][0] * a14.x + hr[r][1] * a14.y + hr[r][2] * a14.z + hr[r][3] * a14.w;
        }
#pragma unroll
        for (int off = 1; off < 16; off <<= 1) {
#pragma unroll
            for (int r = 0; r < 4; ++r) {
                p0[r] += __shfl_xor(p0[r], off);
                p1[r] += __shfl_xor(p1[r], off);
            }
        }
        if (lc == 0) {
#pragma unroll
            for (int r = 0; r < 4; ++r) {
                attp0[w][j0 + r] = p0[r];
                attp1[w][j0 + r] = p1[r];
            }
        }
#pragma unroll
        for (int cc = 0; cc < 4; ++cc) {
            bf16x4_t v;
            v[0] = (bf16_t)hr[0][cc]; v[1] = (bf16_t)hr[1][cc];
            v[2] = (bf16_t)hr[2][cc]; v[3] = (bf16_t)hr[3][cc];
            *(bf16x4_t*)&hT[(c0 + cc) * HSTR + j0] = v;
        }
    }
    __syncthreads();

    // ---- phase 1b ----
    if (t < 80)
        att0s[t] = attp0[0][t] + attp0[1][t] + attp0[2][t] + attp0[3][t];
    else if (t < 160)
        att1s[t - 80] = attp1[0][t - 80] + attp1[1][t - 80] + attp1[2][t - 80] + attp1[3][t - 80];
    else if (t < 240) {
        const int r = t - 160;
        if (r < NN) {
            for (int c = NN; c < 96; ++c) alp[r * ASTR + c] = (bf16_t)0.f;
        } else {
            for (int c = 0; c < 96; ++c) alp[r * ASTR + c] = (bf16_t)0.f;
        }
    }
    __syncthreads();

    // ---- phase S ----
    {
        const int gid = t >> 2;
        const int k4 = t & 3;
#pragma unroll
        for (int r = 0; r < 2; ++r) {
            const int i = r * 64 + gid;
            if (i < NN) {
                const float a0i = att0s[i];
                const u64 w0 = adjb[i * 2];
                const u64 w1 = adjb[i * 2 + 1];
                float e[19];
                float m = -3.0e38f;
#pragma unroll
                for (int jj = 0; jj < 19; ++jj) {
                    const int j = jj * 4 + k4;
                    float ev = -3.0e38f;
                    if (j < NN) {
                        float x = a0i + att1s[j];
                        x = x > 0.f ? x : 0.2f * x;
                        const u64 wj = (j < 64) ? w0 : w1;
                        const int bit = (int)((wj >> (j & 63)) & 1);
                        ev = bit ? x : x - 1.0e9f;
                    }
                    e[jj] = ev;
                    m = fmaxf(m, ev);
                }
                m = fmaxf(m, __shfl_xor(m, 1));
                m = fmaxf(m, __shfl_xor(m, 2));
                float s = 0.f;
#pragma unroll
                for (int jj = 0; jj < 19; ++jj) {
                    const int j = jj * 4 + k4;
                    if (j < NN) {
                        const float ex = __expf(e[jj] - m);
                        s += ex;
                        alp[i * ASTR + j] = (bf16_t)ex;
                    }
                }
                s += __shfl_xor(s, 1);
                s += __shfl_xor(s, 2);
                if (k4 == 0) rsums[i] = 1.f / s;
            }
        }
    }
    __syncthreads();

    // ---- phase P ----
    f32x4 acc2[5][4];
#pragma unroll
    for (int i = 0; i < 5; ++i)
#pragma unroll
        for (int j = 0; j < 4; ++j) acc2[i][j] = (f32x4){0.f, 0.f, 0.f, 0.f};

#pragma unroll
    for (int ks = 0; ks < 3; ++ks) {
        bf16x8 bv[4];
#pragma unroll
        for (int ntl = 0; ntl < 4; ++ntl) {
            const bf16_t* q = &hT[(w * 64 + ntl * 16 + lc) * HSTR + ks * 32 + lr * 8];
            ((uint2*)&bv[ntl])[0] = *(const uint2*)q;
            ((uint2*)&bv[ntl])[1] = *(const uint2*)(q + 4);
        }
#pragma unroll
        for (int mt = 0; mt < 5; ++mt) {
            const bf16_t* ap = &alp[(mt * 16 + lc) * ASTR + ks * 32 + lr * 8];
            bf16x8 av;
            ((uint2*)&av)[0] = *(const uint2*)ap;
            ((uint2*)&av)[1] = *(const uint2*)(ap + 4);
#pragma unroll
            for (int ntl = 0; ntl < 4; ++ntl)
                acc2[mt][ntl] = __builtin_amdgcn_mfma_f32_16x16x32_bf16(av, bv[ntl], acc2[mt][ntl], 0, 0, 0);
        }
    }

    // ---- epilogue ----
#pragma unroll
    for (int mt = 0; mt < 5; ++mt) {
#pragma unroll
        for (int j = 0; j < 4; ++j) {
            const int row = mt * 16 + lr * 4 + j;
            if (row < NN) {
                const float rsv = rsums[row];
#pragma unroll
                for (int ntl = 0; ntl < 4; ++ntl) {
                    const int ch = w * 64 + ntl * 16 + lc;
                    outb[(size_t)row * 512 + ch] = acc2[mt][ntl][j] * rsv;
                }
            }
        }
    }
}

// ---------------------------------------------------------------------------
extern "C" void kernel_launch(void* const* d_in, const int* in_sizes, int n_in,
                              void* d_out, int out_size, void* d_ws, size_t ws_size,
                              hipStream_t stream) {
    const float* X = (const float*)d_in[0];   // [1024,75,512] f32
    const int*   A = (const int*)d_in[1];     // [75,75] i32
    const float* W = (const float*)d_in[2];   // [512,256] f32
    const float* a = (const float*)d_in[3];   // [2,256,1] f32
    float* out = (float*)d_out;               // [1024,75,512] f32
    bf16_t* Wt = (bf16_t*)d_ws;               // 256 KB scratch

    wt_kernel<<<dim3(KF / 64, F1 / 64), 256, 0, stream>>>(W, Wt);
    gemm_kernel<<<(NB * NN) / 64, 256, 0, stream>>>(X, Wt, out);
    pv_kernel<<<NB, 256, 0, stream>>>(A, a, out);
}